// Round 4
// baseline (1796.780 us; speedup 1.0000x reference)
//
#include <hip/hip_runtime.h>
#include <hip/hip_bf16.h>

#define NN 50000
#define NE 500000
#define CD 128
#define HD 256
#define ED 72
#define TE 32            // edges per block
#define CUT 6.0f
#define PI_F 3.14159265358979323846f
#define EPS9 1e-9f

__device__ __forceinline__ float wave_sum64(float v) {
#pragma unroll
  for (int off = 32; off > 0; off >>= 1) v += __shfl_xor(v, off, 64);
  return v;
}

__device__ __forceinline__ float silu(float x) {
  return x / (1.f + __expf(-x));
}

// ---------------- node embedding: LN(z_table[Z]) ----------------
__global__ __launch_bounds__(256) void node_kernel(
    const int* __restrict__ Z, const float* __restrict__ z_table,
    const float* __restrict__ lnw, const float* __restrict__ lnb,
    float* __restrict__ out) {
  int node = (blockIdx.x << 2) + (threadIdx.x >> 6);
  int lane = threadIdx.x & 63;
  if (node >= NN) return;
  int z = Z[node];
  float2 x = *reinterpret_cast<const float2*>(z_table + (size_t)z * CD + lane * 2);
  float s  = wave_sum64(x.x + x.y);
  float sq = wave_sum64(x.x * x.x + x.y * x.y);
  float mu  = s * (1.f / 128.f);
  float var = sq * (1.f / 128.f) - mu * mu;
  float r = rsqrtf(var + 1e-5f);
  float2 w = *reinterpret_cast<const float2*>(lnw + lane * 2);
  float2 b = *reinterpret_cast<const float2*>(lnb + lane * 2);
  float2 o;
  o.x = (x.x - mu) * r * w.x + b.x;
  o.y = (x.y - mu) * r * w.y + b.y;
  *reinterpret_cast<float2*>(out + (size_t)node * CD + lane * 2) = o;
}

// ---------------- fused edge MLP ----------------
// Block = 256 threads = 4 waves, TE=32 edges.
// LDS: buf0/buf1 (32x256 fp32 each). F (32x72) lives in buf0, h1 in buf1,
// h2 back in buf0 (F dead by then). Exactly 64 KiB -> 2 blocks/CU.
__global__ __launch_bounds__(256) void edge_kernel(
    const float* __restrict__ pos, const int* __restrict__ snd,
    const int* __restrict__ rcv,
    const float* __restrict__ W1, const float* __restrict__ b1,
    const float* __restrict__ W2, const float* __restrict__ b2,
    const float* __restrict__ W3, const float* __restrict__ b3,
    const float* __restrict__ lnw, const float* __restrict__ lnb,
    float* __restrict__ out) {
  __shared__ float buf0[TE][HD];
  __shared__ float buf1[TE][HD];
  float (* __restrict__ F)[ED] = reinterpret_cast<float(*)[ED]>(&buf0[0][0]);

  const int t  = threadIdx.x;
  const int e0 = blockIdx.x * TE;

  // ---- geometry: 256 threads = 32 edges x 8 rbf channels ----
  {
    int le = t >> 3;          // local edge
    int j  = t & 7;           // rbf index
    int e  = e0 + le;
    int si = snd[e], ri = rcv[e];
    float vx = pos[3 * ri + 0] - pos[3 * si + 0];
    float vy = pos[3 * ri + 1] - pos[3 * si + 1];
    float vz = pos[3 * ri + 2] - pos[3 * si + 2];
    float d  = sqrtf(vx * vx + vy * vy + vz * vz);
    float inv = 1.f / (d + EPS9);
    float xh = vx * inv, yh = vy * inv, zh = vz * inv;
    const float s3 = 1.7320508075688772f, s5 = 2.23606797749979f,
                s15 = 3.872983346207417f;
    float sh[9];
    sh[0] = 1.f;
    sh[1] = s3 * xh; sh[2] = s3 * yh; sh[3] = s3 * zh;
    sh[4] = s15 * xh * yh;
    sh[5] = s15 * yh * zh;
    sh[6] = 0.5f * s5 * (3.f * zh * zh - 1.f);
    sh[7] = s15 * xh * zh;
    sh[8] = 0.5f * s15 * (xh * xh - yh * yh);
    float xq  = d * (1.f / CUT);
    float xp4 = (xq * xq) * (xq * xq);
    float env = 1.f - 15.f * xp4 + 24.f * xp4 * xq - 10.f * xp4 * xq * xq;
    env = (xq < 1.f) ? env : 0.f;
    // sqrt(2/CUTOFF) = sqrt(1/3)
    float rb = 0.5773502691896258f * sinf((float)(j + 1) * PI_F * d * (1.f / CUT)) * inv;
    float re = rb * env;
#pragma unroll
    for (int m = 0; m < 9; ++m) F[le][j * 9 + m] = re * sh[m];
  }
  __syncthreads();

  const int lane = t & 63;
  const int wg   = t >> 6;   // wave id: owns edges wg*8 .. wg*8+7

  // ---- mm1: F(32x72) @ W1(72x256) + b1 -> silu -> buf1 ----
  {
    float4 bb = *reinterpret_cast<const float4*>(b1 + lane * 4);
    float acc[8][4];
#pragma unroll
    for (int i = 0; i < 8; ++i) {
      acc[i][0] = bb.x; acc[i][1] = bb.y; acc[i][2] = bb.z; acc[i][3] = bb.w;
    }
#pragma unroll 4
    for (int k = 0; k < ED; ++k) {
      float4 w = *reinterpret_cast<const float4*>(W1 + (size_t)k * HD + lane * 4);
#pragma unroll
      for (int i = 0; i < 8; ++i) {
        float f = F[wg * 8 + i][k];
        acc[i][0] += f * w.x; acc[i][1] += f * w.y;
        acc[i][2] += f * w.z; acc[i][3] += f * w.w;
      }
    }
#pragma unroll
    for (int i = 0; i < 8; ++i) {
      float4 o;
      o.x = silu(acc[i][0]); o.y = silu(acc[i][1]);
      o.z = silu(acc[i][2]); o.w = silu(acc[i][3]);
      *reinterpret_cast<float4*>(&buf1[wg * 8 + i][lane * 4]) = o;
    }
  }
  __syncthreads();

  // ---- mm2: h1(32x256) @ W2(256x256) + b2 -> silu -> buf0 ----
  {
    float4 bb = *reinterpret_cast<const float4*>(b2 + lane * 4);
    float acc[8][4];
#pragma unroll
    for (int i = 0; i < 8; ++i) {
      acc[i][0] = bb.x; acc[i][1] = bb.y; acc[i][2] = bb.z; acc[i][3] = bb.w;
    }
#pragma unroll 4
    for (int k = 0; k < HD; ++k) {
      float4 w = *reinterpret_cast<const float4*>(W2 + (size_t)k * HD + lane * 4);
#pragma unroll
      for (int i = 0; i < 8; ++i) {
        float f = buf1[wg * 8 + i][k];
        acc[i][0] += f * w.x; acc[i][1] += f * w.y;
        acc[i][2] += f * w.z; acc[i][3] += f * w.w;
      }
    }
    __syncthreads();   // all waves done reading buf1 before buf0 reuse below
#pragma unroll
    for (int i = 0; i < 8; ++i) {
      float4 o;
      o.x = silu(acc[i][0]); o.y = silu(acc[i][1]);
      o.z = silu(acc[i][2]); o.w = silu(acc[i][3]);
      *reinterpret_cast<float4*>(&buf0[wg * 8 + i][lane * 4]) = o;
    }
  }
  __syncthreads();

  // ---- mm3: h2(32x256) @ W3(256x128) + b3 -> LN -> out ----
  {
    float2 bb = *reinterpret_cast<const float2*>(b3 + lane * 2);
    float acc[8][2];
#pragma unroll
    for (int i = 0; i < 8; ++i) { acc[i][0] = bb.x; acc[i][1] = bb.y; }
#pragma unroll 4
    for (int k = 0; k < HD; ++k) {
      float2 w = *reinterpret_cast<const float2*>(W3 + (size_t)k * CD + lane * 2);
#pragma unroll
      for (int i = 0; i < 8; ++i) {
        float f = buf0[wg * 8 + i][k];
        acc[i][0] += f * w.x; acc[i][1] += f * w.y;
      }
    }
    float2 w = *reinterpret_cast<const float2*>(lnw + lane * 2);
    float2 b = *reinterpret_cast<const float2*>(lnb + lane * 2);
#pragma unroll
    for (int i = 0; i < 8; ++i) {
      float s  = wave_sum64(acc[i][0] + acc[i][1]);
      float sq = wave_sum64(acc[i][0] * acc[i][0] + acc[i][1] * acc[i][1]);
      float mu  = s * (1.f / 128.f);
      float var = sq * (1.f / 128.f) - mu * mu;
      float r = rsqrtf(var + 1e-5f);
      float2 o;
      o.x = (acc[i][0] - mu) * r * w.x + b.x;
      o.y = (acc[i][1] - mu) * r * w.y + b.y;
      *reinterpret_cast<float2*>(
          out + (size_t)(e0 + wg * 8 + i) * CD + lane * 2) = o;
    }
  }
}

extern "C" void kernel_launch(void* const* d_in, const int* in_sizes, int n_in,
                              void* d_out, int out_size, void* d_ws, size_t ws_size,
                              hipStream_t stream) {
  const int*   Z   = (const int*)  d_in[0];
  const float* pos = (const float*)d_in[1];
  const int*   snd = (const int*)  d_in[2];
  const int*   rcv = (const int*)  d_in[3];
  const float* zt  = (const float*)d_in[4];
  const float* zlw = (const float*)d_in[5];
  const float* zlb = (const float*)d_in[6];
  const float* W1  = (const float*)d_in[7];
  const float* b1  = (const float*)d_in[8];
  const float* W2  = (const float*)d_in[9];
  const float* b2  = (const float*)d_in[10];
  const float* W3  = (const float*)d_in[11];
  const float* b3  = (const float*)d_in[12];
  const float* elw = (const float*)d_in[13];
  const float* elb = (const float*)d_in[14];
  float* out = (float*)d_out;

  node_kernel<<<(NN + 3) / 4, 256, 0, stream>>>(Z, zt, zlw, zlb, out);
  edge_kernel<<<NE / TE, 256, 0, stream>>>(pos, snd, rcv, W1, b1, W2, b2,
                                           W3, b3, elw, elb,
                                           out + (size_t)NN * CD);
}